// Round 1
// baseline (184.041 us; speedup 1.0000x reference)
//
#include <hip/hip_runtime.h>

#define EPS_F 1e-7f
#define BONUS 10.0f

__global__ __launch_bounds__(256) void quadinterp3d_kernel(
    const float* __restrict__ x, const float* __restrict__ noise,
    float* __restrict__ out, int B, int D, int H, int W)
{
    int w = blockIdx.x * blockDim.x + threadIdx.x;
    int h = blockIdx.y;
    int bd = blockIdx.z;
    int d = bd % D;
    int b = bd / D;
    if (w >= W) return;

    const long long HW  = (long long)H * W;
    const long long DHW = (long long)D * HW;

    int wm = max(w - 1, 0), wp = min(w + 1, W - 1);
    int hm = max(h - 1, 0), hp = min(h + 1, H - 1);
    int dm = max(d - 1, 0), dp = min(d + 1, D - 1);

    const float* base = x + (long long)b * DHW;

    int ds[3] = {dm, d, dp};
    int hs[3] = {hm, h, hp};
    int wsx[3] = {wm, w, wp};

    float v[3][3][3];
#pragma unroll
    for (int i = 0; i < 3; ++i) {
#pragma unroll
        for (int j = 0; j < 3; ++j) {
            const float* row = base + (long long)ds[i] * HW + (long long)hs[j] * W;
#pragma unroll
            for (int k = 0; k < 3; ++k) v[i][j][k] = row[wsx[k]];
        }
    }

    float c = v[1][1][1];

    // gradients (kornia diff mode; depth kernel flipped -> gz sign)
    float gx = 0.5f * (v[1][1][2] - v[1][1][0]);
    float gy = 0.5f * (v[1][2][1] - v[1][0][1]);
    float gz = 0.5f * (v[0][1][1] - v[2][1][1]);

    // second-order
    float dxx = v[1][1][2] - 2.0f * c + v[1][1][0];
    float dyy = v[1][2][1] - 2.0f * c + v[1][0][1];
    float dss = v[2][1][1] - 2.0f * c + v[0][1][1];
    float dxy = 0.25f * (v[1][0][0] - v[1][0][2] - v[1][2][0] + v[1][2][2]);
    float dys = 0.25f * (v[2][0][1] - v[2][2][1] - v[0][0][1] + v[0][2][1]);
    float dxs = 0.25f * (v[2][1][0] - v[2][1][2] - v[0][1][0] + v[0][1][2]);

    // strict-NMS: c is the max of the (clamped) 27-neighborhood.
    // Clamped max == (-inf)-padded max because every clamped neighbor
    // aliases an in-range member of the window.
    float mx27 = c;
#pragma unroll
    for (int i = 0; i < 3; ++i)
#pragma unroll
        for (int j = 0; j < 3; ++j)
#pragma unroll
            for (int k = 0; k < 3; ++k) mx27 = fmaxf(mx27, v[i][j][k]);
    bool mask = (c == mx27);

    float dx0 = 0.0f, dx1 = 0.0f, dx2 = 0.0f, dy = 0.0f;

    if (mask) {
        // Hessian + asymmetric noise guard
        float A[3][3];
        float rhs[3];
        A[0][0] = dxx + noise[0] * EPS_F;
        A[0][1] = dxy + noise[1] * EPS_F;
        A[0][2] = dxs + noise[2] * EPS_F;
        A[1][0] = dxy + noise[3] * EPS_F;
        A[1][1] = dyy + noise[4] * EPS_F;
        A[1][2] = dys + noise[5] * EPS_F;
        A[2][0] = dxs + noise[6] * EPS_F;
        A[2][1] = dys + noise[7] * EPS_F;
        A[2][2] = dss + noise[8] * EPS_F;
        rhs[0] = gx; rhs[1] = gy; rhs[2] = gz;

        // 3x3 Gaussian elimination w/ partial pivoting (LAPACK gesv order)
        // column 0 pivot
        {
            int p = 0; float am = fabsf(A[0][0]);
            if (fabsf(A[1][0]) > am) { am = fabsf(A[1][0]); p = 1; }
            if (fabsf(A[2][0]) > am) { p = 2; }
            if (p != 0) {
#pragma unroll
                for (int j = 0; j < 3; ++j) { float t = A[0][j]; A[0][j] = A[p][j]; A[p][j] = t; }
                float t = rhs[0]; rhs[0] = rhs[p]; rhs[p] = t;
            }
            float m1 = A[1][0] / A[0][0];
            float m2 = A[2][0] / A[0][0];
            A[1][1] -= m1 * A[0][1]; A[1][2] -= m1 * A[0][2]; rhs[1] -= m1 * rhs[0];
            A[2][1] -= m2 * A[0][1]; A[2][2] -= m2 * A[0][2]; rhs[2] -= m2 * rhs[0];
        }
        // column 1 pivot
        {
            if (fabsf(A[2][1]) > fabsf(A[1][1])) {
                float t;
                t = A[1][1]; A[1][1] = A[2][1]; A[2][1] = t;
                t = A[1][2]; A[1][2] = A[2][2]; A[2][2] = t;
                t = rhs[1]; rhs[1] = rhs[2]; rhs[2] = t;
            }
            float m = A[2][1] / A[1][1];
            A[2][2] -= m * A[1][2]; rhs[2] -= m * rhs[1];
        }
        // back substitution
        float s2 = rhs[2] / A[2][2];
        float s1 = (rhs[1] - A[1][2] * s2) / A[1][1];
        float s0 = (rhs[0] - A[0][1] * s1 - A[0][2] * s2) / A[0][0];

        dx0 = -s0; dx1 = -s1; dx2 = -s2;
        float amax = fmaxf(fabsf(dx0), fmaxf(fabsf(dx1), fabsf(dx2)));
        if (amax > 0.7f) { dx0 = 0.0f; dx1 = 0.0f; dx2 = 0.0f; }
        dy = 0.5f * (gx * dx0 + gy * dx1 + gz * dx2);
    }

    long long spatial = (long long)d * HW + (long long)h * W + w;
    // coords_max: (B, C=1, 3, D, H, W); channel order (d,h,w) = dx[::-1]
    float* oc = out + (long long)b * 3 * DHW + spatial;
    oc[0]       = (float)d + dx2;
    oc[DHW]     = (float)h + dx1;
    oc[2 * DHW] = (float)w + dx0;
    // y_max: after all coords
    float* oy = out + (long long)B * 3 * DHW + (long long)b * DHW + spatial;
    oy[0] = c + dy + (mask ? BONUS : 0.0f);
}

extern "C" void kernel_launch(void* const* d_in, const int* in_sizes, int n_in,
                              void* d_out, int out_size, void* d_ws, size_t ws_size,
                              hipStream_t stream) {
    const float* x     = (const float*)d_in[0];
    const float* noise = (const float*)d_in[1];
    float* out = (float*)d_out;

    const int B = 2, D = 4, H = 1024, W = 1024;

    dim3 block(256, 1, 1);
    dim3 grid(W / 256, H, B * D);
    quadinterp3d_kernel<<<grid, block, 0, stream>>>(x, noise, out, B, D, H, W);
}